// Round 14
// baseline (246.879 us; speedup 1.0000x reference)
//
#include <hip/hip_runtime.h>
#include <hip/hip_bf16.h>

#define D_MODEL 1024
#define SEQ     2048
#define BATCH   4
#define NH      16
#define DHEAD   64

typedef __attribute__((ext_vector_type(8))) short bhalf8;
typedef __attribute__((ext_vector_type(4))) float floatx4;
typedef __attribute__((ext_vector_type(16))) float floatx16;
typedef __attribute__((ext_vector_type(4))) unsigned int uintx4;
typedef __attribute__((ext_vector_type(2))) unsigned int uintx2;
typedef __attribute__((ext_vector_type(8))) unsigned short ushort8v;

__device__ __forceinline__ void gload16(const void* g, void* l) {
  __builtin_amdgcn_global_load_lds(
      (const __attribute__((address_space(1))) unsigned int*)g,
      (__attribute__((address_space(3))) unsigned int*)l, 16, 0, 0);
}

__device__ __forceinline__ unsigned short f2bf(float x) {
  __hip_bfloat16 h = __float2bfloat16(x);
  return __builtin_bit_cast(unsigned short, h);
}

// lane-half exchange: out[0]={a.row0, b.row0}, out[1]={a.row1, b.row1}
__device__ __forceinline__ uintx2 pl32(unsigned int a, unsigned int b) {
  return __builtin_amdgcn_permlane32_swap(a, b, false, false);
}

// ---------------- fp32 -> bf16 convert, generic (fallback path) -----------
__global__ void cvt_bf16_kernel(const float* __restrict__ in,
                                unsigned short* __restrict__ out, int n4) {
  int i = blockIdx.x * blockDim.x + threadIdx.x;
  if (i >= n4) return;
  float4 v = ((const float4*)in)[i];
  ushort4 o;
  o.x = f2bf(v.x); o.y = f2bf(v.y); o.z = f2bf(v.z); o.w = f2bf(v.w);
  ((ushort4*)out)[i] = o;
}

// ---------------- fused convert, 32B/lane: q/k/v + 4 weight matrices ------
__global__ void cvt_all_kernel(const float* __restrict__ q, const float* __restrict__ k,
                               const float* __restrict__ v, const float* __restrict__ wq,
                               const float* __restrict__ wk, const float* __restrict__ wv,
                               const float* __restrict__ wo,
                               unsigned short* __restrict__ xq, unsigned short* __restrict__ xk,
                               unsigned short* __restrict__ xv, unsigned short* __restrict__ wqb,
                               unsigned short* __restrict__ wkb, unsigned short* __restrict__ wvb,
                               unsigned short* __restrict__ wob) {
  const int L = blockIdx.x;
  const float* src;
  unsigned short* dst;
  int base;
  if      (L < 4096)  { src = q;  dst = xq;  base = 0; }
  else if (L < 8192)  { src = k;  dst = xk;  base = 4096; }
  else if (L < 12288) { src = v;  dst = xv;  base = 8192; }
  else if (L < 12800) { src = wq; dst = wqb; base = 12288; }
  else if (L < 13312) { src = wk; dst = wkb; base = 12800; }
  else if (L < 13824) { src = wv; dst = wvb; base = 13312; }
  else                { src = wo; dst = wob; base = 13824; }
  const int i = (L - base) * 256 + threadIdx.x;   // 32B-pair index
  const float4 v0 = ((const float4*)src)[2 * i];
  const float4 v1 = ((const float4*)src)[2 * i + 1];
  ushort8v o;
  o[0] = f2bf(v0.x); o[1] = f2bf(v0.y); o[2] = f2bf(v0.z); o[3] = f2bf(v0.w);
  o[4] = f2bf(v1.x); o[5] = f2bf(v1.y); o[6] = f2bf(v1.z); o[7] = f2bf(v1.w);
  ((ushort8v*)dst)[i] = o;
}

// ---------------- mask dtype detection (bool push format is ambiguous) ----
__global__ void detect_mask_kernel(const unsigned int* __restrict__ m,
                                   unsigned int* __restrict__ flag) {
  __shared__ unsigned int not_int, not_flt;
  if (threadIdx.x == 0) { not_int = 0u; not_flt = 0u; }
  __syncthreads();
  unsigned int ni = 0u, nf = 0u;
  for (int j = 0; j < 4; ++j) {
    unsigned int w = m[threadIdx.x * 4 + j];
    if (w > 1u) ni = 1u;
    if (w != 0u && w != 0x3f800000u) nf = 1u;
  }
  if (ni) atomicOr(&not_int, 1u);
  if (nf) atomicOr(&not_flt, 1u);
  __syncthreads();
  if (threadIdx.x == 0) {
    unsigned int f = 1u;
    if (!not_int) f = 0u;
    else if (!not_flt) f = 2u;
    *flag = f;
  }
}

// ---------------- bit-pack mask: bit=1 <=> KEEP; 8 words per wave ---------
__global__ void pack_mask_kernel(const void* __restrict__ mraw,
                                 const unsigned int* __restrict__ flag,
                                 unsigned long long* __restrict__ bits) {
  const unsigned int f = *flag;
  const int lane = threadIdx.x & 63;
  const int w0 = ((blockIdx.x * blockDim.x + threadIdx.x) >> 6) * 8;
#pragma unroll
  for (int e = 0; e < 8; ++e) {
    const int t = (w0 + e) * 64 + lane;
    int v;
    if (f == 1u) v = (((const unsigned char*)mraw)[t] != 0);
    else         v = (((const unsigned int*)mraw)[t] != 0u);
    const unsigned long long b = __ballot(v == 0);   // keep-bit
    if (lane == 0) bits[w0 + e] = b;
  }
}

// ---------------- GEMM core, K=1024, BK=64, 2-phase prefetch --------------
template <int F32OUT>
__device__ __forceinline__ void gemm_core(const unsigned short* __restrict__ A,
                                          const unsigned short* __restrict__ B,
                                          const float* __restrict__ bias,
                                          void* __restrict__ Cout,
                                          int N, float scale, int biasM, int L) {
  __shared__ unsigned short As[2][128][64];   // 32KB, XOR-swizzled rows
  __shared__ unsigned short Bs[2][128][64];   // 32KB
  const int tid = threadIdx.x;
  const int wid = tid >> 6, lane = tid & 63;
  const int g = lane >> 4, c = lane & 15;
  const int wr = wid >> 1, wc = wid & 1;

  // XCD-pin swizzle (L%8 = xcd on MI355X): bijective L(0..511) -> (bx,by)
  const int xcd = L & 7;
  const int i5 = L >> 3;              // 0..63
  const int u = i5 & 7, v5 = i5 >> 3; // 0..7 each
  int bx, by;
  if ((N >> 7) == 8) { bx = u; by = xcd + 8 * v5; }   // 8x64 grid: pin A-row panel
  else               { bx = xcd + 8 * u; by = v5; }   // 64x8 grid: pin B-col panel
  const int m0 = by * 128, n0 = bx * 128;

  const floatx4 zero4 = {0.f, 0.f, 0.f, 0.f};
  floatx4 acc[4][4];
#pragma unroll
  for (int i = 0; i < 4; ++i)
#pragma unroll
    for (int j = 0; j < 4; ++j) acc[i][j] = zero4;

  const int r_ = tid >> 3;                                  // 0..31
  const int sb = ((tid & 7) * 16) ^ (((tid >> 3) & 7) << 4);
  const char* Asrc = (const char*)(A + (size_t)(m0 + r_) * 1024) + sb;
  const char* Bsrc = (const char*)(B + (size_t)(n0 + r_) * 1024) + sb;
  const size_t ROWP = (size_t)32 * 1024 * 2;

  auto stage = [&](int kt, int buf) {
    const size_t ko = (size_t)kt * 128;
#pragma unroll
    for (int p = 0; p < 4; ++p) {
      gload16(Asrc + ko + p * ROWP, (char*)&As[buf][0][0] + p * 4096 + tid * 16);
      gload16(Bsrc + ko + p * ROWP, (char*)&Bs[buf][0][0] + p * 4096 + tid * 16);
    }
  };

  stage(0, 0);
  __syncthreads();
  int cur = 0;
  for (int kt = 0; kt < 16; ++kt) {
    if (kt + 1 < 16) stage(kt + 1, cur ^ 1);   // loads fly across compute
    const char* abase = (const char*)&As[cur][0][0];
    const char* bbase = (const char*)&Bs[cur][0][0];
    bhalf8 a[2][4], b[2][4];
#pragma unroll
    for (int kk = 0; kk < 2; ++kk) {
#pragma unroll
      for (int i = 0; i < 4; ++i) {
        const int row = wr * 64 + i * 16 + c;
        a[kk][i] = *(const bhalf8*)(abase + row * 128 +
                                    ((kk * 64 + g * 16) ^ ((row & 7) << 4)));
      }
#pragma unroll
      for (int j = 0; j < 4; ++j) {
        const int row = wc * 64 + j * 16 + c;
        b[kk][j] = *(const bhalf8*)(bbase + row * 128 +
                                    ((kk * 64 + g * 16) ^ ((row & 7) << 4)));
      }
    }
#pragma unroll
    for (int kk = 0; kk < 2; ++kk)
#pragma unroll
      for (int i = 0; i < 4; ++i)
#pragma unroll
        for (int j = 0; j < 4; ++j)
          acc[i][j] = __builtin_amdgcn_mfma_f32_16x16x32_bf16(a[kk][i], b[kk][j], acc[i][j], 0, 0, 0);
    __syncthreads();
    cur ^= 1;
  }

  float bn[4] = {0.f, 0.f, 0.f, 0.f};
  if (!biasM) {
#pragma unroll
    for (int j = 0; j < 4; ++j) bn[j] = bias[n0 + wc * 64 + j * 16 + c];
  }
#pragma unroll
  for (int i = 0; i < 4; ++i) {
    float bm[4] = {0.f, 0.f, 0.f, 0.f};
    if (biasM) {
#pragma unroll
      for (int r = 0; r < 4; ++r) bm[r] = bias[m0 + wr * 64 + i * 16 + 4 * g + r];
    }
#pragma unroll
    for (int j = 0; j < 4; ++j) {
#pragma unroll
      for (int r = 0; r < 4; ++r) {
        const int m = m0 + wr * 64 + i * 16 + 4 * g + r;
        const int n = n0 + wc * 64 + j * 16 + c;
        const float v = (acc[i][j][r] + (biasM ? bm[r] : bn[j])) * scale;
        if (F32OUT) ((float*)Cout)[(size_t)m * N + n] = v;
        else ((unsigned short*)Cout)[(size_t)m * N + n] = f2bf(v);
      }
    }
  }
}

// merged QKV projections: jsel==3 -> grid 1536, j = L>>9; else j = jsel, grid 512
__global__ __launch_bounds__(256, 2)
void gemm_qkv_kernel(const unsigned short* __restrict__ Xq,
                     const unsigned short* __restrict__ Xk,
                     const unsigned short* __restrict__ Xv,
                     const unsigned short* __restrict__ Wqb,
                     const unsigned short* __restrict__ Wkb,
                     const unsigned short* __restrict__ Wvb,
                     const float* __restrict__ bq, const float* __restrict__ bk,
                     const float* __restrict__ bv,
                     unsigned short* __restrict__ Qb, unsigned short* __restrict__ Kb,
                     unsigned short* __restrict__ Vtb, float qscale, int jsel) {
  int j, L;
  if (jsel == 3) { j = blockIdx.x >> 9; L = blockIdx.x & 511; }
  else           { j = jsel; L = blockIdx.x; }
  const unsigned short* A = (j == 0) ? Xq : (j == 1) ? Xk : Wvb;
  const unsigned short* B = (j == 0) ? Wqb : (j == 1) ? Wkb : Xv;
  const float* bias = (j == 0) ? bq : (j == 1) ? bk : bv;
  unsigned short* C = (j == 0) ? Qb : (j == 1) ? Kb : Vtb;
  const int N = (j == 2) ? 8192 : 1024;
  const float scale = (j == 0) ? qscale : 1.0f;
  gemm_core<0>(A, B, bias, C, N, scale, (j == 2) ? 1 : 0, L);
}

__global__ __launch_bounds__(256, 2)
void gemm_out_kernel(const unsigned short* __restrict__ A,
                     const unsigned short* __restrict__ B,
                     const float* __restrict__ bias, float* __restrict__ C) {
  gemm_core<1>(A, B, bias, C, 1024, 1.0f, 0, blockIdx.x);
}

// ---------------- flash attention, 8 waves x 32 q-rows, 32x32x16 MFMA ------
// R14: KVBLK=128 as TWO structure-identical 64-kv subtiles per barrier:
// per-subtile body (koff, swizzle, SM, PV) byte-identical to R13; one
// __syncthreads per 128 kv -> barrier drains 32 -> 16, prefetch distance 2x.
// Swapped QK^T; no max tracking; denominator via ones-column MFMA; KEEP-bit
// mask via sbfe+and; permlane32_swap A-frag exchange; XCD-pin swizzle.
__global__ __launch_bounds__(512, 2)
void attn_kernel(const unsigned short* __restrict__ Q,
                 const unsigned short* __restrict__ Kmat,
                 const unsigned short* __restrict__ Vt,
                 const unsigned long long* __restrict__ mbits,
                 unsigned short* __restrict__ O) {
  __shared__ unsigned short Ks[2][2][64][64];   // [buf][sub][kv][dh], swizzled
  __shared__ unsigned short Vs[2][2][64][64];   // [buf][sub][d][kv],  swizzled

  const int tid = threadIdx.x;
  const int wid = tid >> 6, lane = tid & 63;
  const int ql = lane & 31;
  const int hi = lane >> 5;

  // XCD-pin swizzle: xcd = L&7 (HW round-robin), bh fixed per xcd
  const int L = blockIdx.x;          // 0..511
  const int xcd = L & 7;
  const int s = L >> 3;              // 0..63
  const int bh = (s & 7) * 8 + xcd;  // 8 bh-streams per XCD
  const int qt = s >> 3;             // 0..7
  const int b = bh >> 4, h = bh & 15;
  const int q0 = qt * 256 + wid * 32;

  const unsigned short* Qb = Q + (size_t)(b * SEQ + q0) * D_MODEL + h * DHEAD;
  const unsigned short* Kb = Kmat + (size_t)(b * SEQ) * D_MODEL + h * DHEAD;
  const unsigned short* Vb = Vt + (size_t)(h * DHEAD) * (BATCH * SEQ) + (size_t)b * SEQ;

  // Q fragments: B-frag col=q=lane&31, k=dh=(lane>>5)*8+j
  bhalf8 qf[4];
#pragma unroll
  for (int ks = 0; ks < 4; ++ks)
    qf[ks] = *(const bhalf8*)(Qb + (size_t)ql * D_MODEL + ks * 16 + hi * 8);

  const floatx16 z16 = {0,0,0,0,0,0,0,0,0,0,0,0,0,0,0,0};
  floatx16 ot[2];
  ot[0] = z16; ot[1] = z16;
  floatx16 lt = z16;                       // softmax denominators (ones-MFMA)

  const short ONEB = (short)0x3F80;        // bf16 1.0
  const bhalf8 ones8 = {ONEB, ONEB, ONEB, ONEB, ONEB, ONEB, ONEB, ONEB};

  int koff[4];
#pragma unroll
  for (int ks = 0; ks < 4; ++ks)
    koff[ks] = ql * 128 + ((ks * 32 + hi * 16) ^ ((ql & 7) << 4));

  // staging: per 128-kv big tile, each thread: 2 gload16 K + 2 gload16 V.
  // Subtile sub covers kv rows [sub*64, sub*64+64) (K) / kv cols (V).
  const int sr = tid >> 3;                               // row 0..63
  const int sbz = ((tid & 7) * 16) ^ ((sr & 7) << 4);    // pre-swizzled src byte
  const char* Ksrc = (const char*)(Kb + (size_t)sr * D_MODEL) + sbz;
  const char* Vsrc = (const char*)(Vb + (size_t)sr * (BATCH * SEQ)) + sbz;
  const size_t KSUB = (size_t)64 * D_MODEL * 2;          // 64 kv rows of K
  const size_t KSTEP = 2 * KSUB;                         // 128 kv rows
  const size_t VSUB = 128;                               // 64 kv cols (bytes)
  const size_t VSTEP = 256;

  const int NT2 = SEQ / 128;
  gload16(Ksrc,        (char*)&Ks[0][0][0][0] + tid * 16);
  gload16(Ksrc + KSUB, (char*)&Ks[0][1][0][0] + tid * 16);
  gload16(Vsrc,        (char*)&Vs[0][0][0][0] + tid * 16);
  gload16(Vsrc + VSUB, (char*)&Vs[0][1][0][0] + tid * 16);
  __syncthreads();
  const char* kp = Ksrc + KSTEP;
  const char* vp = Vsrc + VSTEP;
  const unsigned long long* mp = mbits + (size_t)(q0 + ql) * (SEQ / 64);
  int cur = 0;

  for (int kt = 0; kt < NT2; ++kt) {
    if (kt + 1 < NT2) {
      gload16(kp,        (char*)&Ks[cur ^ 1][0][0][0] + tid * 16);
      gload16(kp + KSUB, (char*)&Ks[cur ^ 1][1][0][0] + tid * 16);
      gload16(vp,        (char*)&Vs[cur ^ 1][0][0][0] + tid * 16);
      gload16(vp + VSUB, (char*)&Vs[cur ^ 1][1][0][0] + tid * 16);
      kp += KSTEP;
      vp += VSTEP;
    }

#pragma unroll
    for (int sub = 0; sub < 2; ++sub) {
      const unsigned long long mws = mp[2 * kt + sub] >> (4 * hi);  // keep-bits
      const unsigned int mlo = (unsigned int)mws;
      const unsigned int mhi32 = (unsigned int)(mws >> 32);

      const char* kbase = (const char*)&Ks[cur][sub][0][0];
      const char* vbase = (const char*)&Vs[cur][sub][0][0];

      // S^T = K * Q^T (first ks uses z16 as C-in -> no per-tile zero movs)
      floatx16 st[2];
      __builtin_amdgcn_s_setprio(1);
#pragma unroll
      for (int blk = 0; blk < 2; ++blk) {
        const bhalf8 kf0 = *(const bhalf8*)(kbase + koff[0] + blk * 4096);
        st[blk] = __builtin_amdgcn_mfma_f32_32x32x16_bf16(kf0, qf[0], z16, 0, 0, 0);
      }
#pragma unroll
      for (int ks = 1; ks < 4; ++ks) {
#pragma unroll
        for (int blk = 0; blk < 2; ++blk) {
          const bhalf8 kf = *(const bhalf8*)(kbase + koff[ks] + blk * 4096);
          st[blk] = __builtin_amdgcn_mfma_f32_32x32x16_bf16(kf, qf[ks], st[blk], 0, 0, 0);
        }
      }
      __builtin_amdgcn_s_setprio(0);

      // P = exp2(S), zero non-keep via sbfe(0/-1)+and, pack pairs (f2bf RNE)
      unsigned int w[2][8];
#pragma unroll
      for (int blk = 0; blk < 2; ++blk) {
        const unsigned int word = blk ? mhi32 : mlo;
#pragma unroll
        for (int i = 0; i < 8; ++i) {
          const int r0 = 2 * i, r1 = 2 * i + 1;
          const int c0 = (r0 & 3) + 8 * (r0 >> 2);
          const int c1 = c0 + 1;
          float p0 = __builtin_amdgcn_exp2f(st[blk][r0]);
          float p1 = __builtin_amdgcn_exp2f(st[blk][r1]);
          const unsigned int e0 = (unsigned int)__builtin_amdgcn_sbfe((int)word, c0, 1);
          const unsigned int e1 = (unsigned int)__builtin_amdgcn_sbfe((int)word, c1, 1);
          p0 = __builtin_bit_cast(float, __builtin_bit_cast(unsigned int, p0) & e0);
          p1 = __builtin_bit_cast(float, __builtin_bit_cast(unsigned int, p1) & e1);
          w[blk][i] = ((unsigned int)f2bf(p1) << 16) | (unsigned int)f2bf(p0);
        }
      }

      // O += P V; lt += P * ones. A-frags via permlane32_swap.
      __builtin_amdgcn_s_setprio(1);
#pragma unroll
      for (int blk = 0; blk < 2; ++blk)
#pragma unroll
        for (int s2 = 0; s2 < 2; ++s2) {
          const int ks = blk * 2 + s2;
          const int o = s2 * 4;
          const uintx2 u2 = pl32(w[blk][o + 0], w[blk][o + 2]);
          const uintx2 v2 = pl32(w[blk][o + 1], w[blk][o + 3]);
          uintx4 awv;
          awv[0] = u2[0];  awv[1] = v2[0];  awv[2] = u2[1];  awv[3] = v2[1];
          const bhalf8 pa = __builtin_bit_cast(bhalf8, awv);
#pragma unroll
          for (int db = 0; db < 2; ++db) {
            const bhalf8 vf = *(const bhalf8*)(vbase + koff[ks] + db * 4096);
            ot[db] = __builtin_amdgcn_mfma_f32_32x32x16_bf16(pa, vf, ot[db], 0, 0, 0);
          }
          lt = __builtin_amdgcn_mfma_f32_32x32x16_bf16(pa, ones8, lt, 0, 0, 0);
        }
      __builtin_amdgcn_s_setprio(0);
    }

    __syncthreads();   // one drain per 128 kv (was per 64)
    cur ^= 1;
  }

  // epilogue: O / l, write bf16 [b*T+q][h*64+d]
#pragma unroll
  for (int r = 0; r < 16; ++r) {
    const int qr = (r & 3) + 8 * (r >> 2) + 4 * hi;
    const float fi = 1.f / lt[r];
    unsigned short* orow = O + (size_t)(b * SEQ + q0 + qr) * D_MODEL + h * DHEAD + ql;
    orow[0]  = f2bf(ot[0][r] * fi);
    orow[32] = f2bf(ot[1][r] * fi);
  }
}

extern "C" void kernel_launch(void* const* d_in, const int* in_sizes, int n_in,
                              void* d_out, int out_size, void* d_ws, size_t ws_size,
                              hipStream_t stream) {
  (void)in_sizes; (void)n_in; (void)out_size;
  const float* query = (const float*)d_in[0];
  const float* key   = (const float*)d_in[1];
  const float* value = (const float*)d_in[2];
  const void*  mask  = d_in[3];
  const float* Wq = (const float*)d_in[4];
  const float* bq = (const float*)d_in[5];
  const float* Wk = (const float*)d_in[6];
  const float* bk = (const float*)d_in[7];
  const float* Wv = (const float*)d_in[8];
  const float* bv = (const float*)d_in[9];
  const float* Wo = (const float*)d_in[10];
  const float* bo = (const float*)d_in[11];

  const float QSCALE = 1.4426950408889634f / 32.0f;  // log2e / sqrt(D)
  const size_t XB = (size_t)8192 * 1024 * 2;          // 16 MB
  const size_t WB = (size_t)1024 * 1024 * 2;          // 2 MB
  const size_t MB = (size_t)2048 * 32 * 8;            // 512 KB

  char* ws = (char*)d_ws;
  size_t off = 0;
  auto alloc = [&](size_t bytes) {
    char* p = ws + off;
    off += (bytes + 255) & ~(size_t)255;
    return p;
  };

  // -------- path A: fused launches (needs ~105 MB) --------
  {
    size_t o2 = 0;
    auto need = [&](size_t b) { o2 += (b + 255) & ~(size_t)255; };
    need(XB); need(XB); need(XB);                 // Xq Xk Xv
    need(WB); need(WB); need(WB); need(WB);       // Wqb Wkb Wvb Wob
    need(XB); need(XB); need(XB);                 // Qb Kbf Vtb  (Ob aliases Xq)
    need(MB); need(256);
    if (o2 <= ws_size) {
      unsigned short* Xq  = (unsigned short*)alloc(XB);
      unsigned short* Xk  = (unsigned short*)alloc(XB);
      unsigned short* Xv  = (unsigned short*)alloc(XB);
      unsigned short* Wqb = (unsigned short*)alloc(WB);
      unsigned short* Wkb = (unsigned short*)alloc(WB);
      unsigned short* Wvb = (unsigned short*)alloc(WB);
      unsigned short* Wob = (unsigned short*)alloc(WB);
      unsigned short* Qb  = (unsigned short*)alloc(XB);
      unsigned short* Kbf = (unsigned short*)alloc(XB);
      unsigned short* Vtb = (unsigned short*)alloc(XB);
      unsigned long long* mbits = (unsigned long long*)alloc(MB);
      unsigned int* flag = (unsigned int*)alloc(256);
      unsigned short* Ob = Xq;   // lifetimes disjoint: Xq dead after gemm_qkv

      detect_mask_kernel<<<1, 256, 0, stream>>>((const unsigned int*)mask, flag);
      pack_mask_kernel<<<2048, 256, 0, stream>>>(mask, flag, mbits);
      cvt_all_kernel<<<14336, 256, 0, stream>>>(query, key, value, Wq, Wk, Wv, Wo,
                                                Xq, Xk, Xv, Wqb, Wkb, Wvb, Wob);
      gemm_qkv_kernel<<<1536, 256, 0, stream>>>(Xq, Xk, Xv, Wqb, Wkb, Wvb,
                                                bq, bk, bv, Qb, Kbf, Vtb, QSCALE, 3);
      attn_kernel<<<512, 512, 0, stream>>>(Qb, Kbf, Vtb, mbits, Ob);
      gemm_out_kernel<<<512, 256, 0, stream>>>(Ob, Wob, bo, (float*)d_out);
      return;
    }
  }

  // -------- path B: sequential, shared X buffer (~83 MB) --------
  unsigned short* Xb  = (unsigned short*)alloc(XB);
  unsigned short* Wb  = (unsigned short*)alloc(WB);
  unsigned short* Qb  = (unsigned short*)alloc(XB);
  unsigned short* Kbf = (unsigned short*)alloc(XB);
  unsigned short* Vtb = (unsigned short*)alloc(XB);
  unsigned short* Ob  = (unsigned short*)alloc(XB);
  unsigned long long* mbits = (unsigned long long*)alloc(MB);
  unsigned int* flag = (unsigned int*)alloc(256);
  if (off > ws_size) return;

  detect_mask_kernel<<<1, 256, 0, stream>>>((const unsigned int*)mask, flag);
  pack_mask_kernel<<<2048, 256, 0, stream>>>(mask, flag, mbits);

  cvt_bf16_kernel<<<8192, 256, 0, stream>>>(query, Xb, 2097152);
  cvt_bf16_kernel<<<1024, 256, 0, stream>>>(Wq, Wb, 262144);
  gemm_qkv_kernel<<<512, 256, 0, stream>>>(Xb, Xb, Xb, Wb, Wb, Wb, bq, bk, bv,
                                           Qb, Kbf, Vtb, QSCALE, 0);
  cvt_bf16_kernel<<<8192, 256, 0, stream>>>(key, Xb, 2097152);
  cvt_bf16_kernel<<<1024, 256, 0, stream>>>(Wk, Wb, 262144);
  gemm_qkv_kernel<<<512, 256, 0, stream>>>(Xb, Xb, Xb, Wb, Wb, Wb, bq, bk, bv,
                                           Qb, Kbf, Vtb, QSCALE, 1);
  cvt_bf16_kernel<<<8192, 256, 0, stream>>>(value, Xb, 2097152);
  cvt_bf16_kernel<<<1024, 256, 0, stream>>>(Wv, Wb, 262144);
  gemm_qkv_kernel<<<512, 256, 0, stream>>>(Xb, Xb, Xb, Wb, Wb, Wb, bq, bk, bv,
                                           Qb, Kbf, Vtb, QSCALE, 2);
  attn_kernel<<<512, 512, 0, stream>>>(Qb, Kbf, Vtb, mbits, Ob);
  cvt_bf16_kernel<<<1024, 256, 0, stream>>>(Wo, Wb, 262144);
  gemm_out_kernel<<<512, 256, 0, stream>>>(Ob, Wb, bo, (float*)d_out);
}

// Round 15
// 231.674 us; speedup vs baseline: 1.0656x; 1.0656x over previous
//
#include <hip/hip_runtime.h>
#include <hip/hip_bf16.h>

#define D_MODEL 1024
#define SEQ     2048
#define BATCH   4
#define NH      16
#define DHEAD   64

typedef __attribute__((ext_vector_type(8))) short bhalf8;
typedef __attribute__((ext_vector_type(4))) float floatx4;
typedef __attribute__((ext_vector_type(16))) float floatx16;
typedef __attribute__((ext_vector_type(4))) unsigned int uintx4;
typedef __attribute__((ext_vector_type(2))) unsigned int uintx2;
typedef __attribute__((ext_vector_type(8))) unsigned short ushort8v;

__device__ __forceinline__ void gload16(const void* g, void* l) {
  __builtin_amdgcn_global_load_lds(
      (const __attribute__((address_space(1))) unsigned int*)g,
      (__attribute__((address_space(3))) unsigned int*)l, 16, 0, 0);
}

__device__ __forceinline__ unsigned short f2bf(float x) {
  __hip_bfloat16 h = __float2bfloat16(x);
  return __builtin_bit_cast(unsigned short, h);
}

// lane-half exchange: out[0]={a.row0, b.row0}, out[1]={a.row1, b.row1}
__device__ __forceinline__ uintx2 pl32(unsigned int a, unsigned int b) {
  return __builtin_amdgcn_permlane32_swap(a, b, false, false);
}

// ---------------- fp32 -> bf16 convert, generic (fallback path) -----------
__global__ void cvt_bf16_kernel(const float* __restrict__ in,
                                unsigned short* __restrict__ out, int n4) {
  int i = blockIdx.x * blockDim.x + threadIdx.x;
  if (i >= n4) return;
  float4 v = ((const float4*)in)[i];
  ushort4 o;
  o.x = f2bf(v.x); o.y = f2bf(v.y); o.z = f2bf(v.z); o.w = f2bf(v.w);
  ((ushort4*)out)[i] = o;
}

// ---------------- fused convert, 32B/lane: q/k/v + 4 weight matrices ------
__global__ void cvt_all_kernel(const float* __restrict__ q, const float* __restrict__ k,
                               const float* __restrict__ v, const float* __restrict__ wq,
                               const float* __restrict__ wk, const float* __restrict__ wv,
                               const float* __restrict__ wo,
                               unsigned short* __restrict__ xq, unsigned short* __restrict__ xk,
                               unsigned short* __restrict__ xv, unsigned short* __restrict__ wqb,
                               unsigned short* __restrict__ wkb, unsigned short* __restrict__ wvb,
                               unsigned short* __restrict__ wob) {
  const int L = blockIdx.x;
  const float* src;
  unsigned short* dst;
  int base;
  if      (L < 4096)  { src = q;  dst = xq;  base = 0; }
  else if (L < 8192)  { src = k;  dst = xk;  base = 4096; }
  else if (L < 12288) { src = v;  dst = xv;  base = 8192; }
  else if (L < 12800) { src = wq; dst = wqb; base = 12288; }
  else if (L < 13312) { src = wk; dst = wkb; base = 12800; }
  else if (L < 13824) { src = wv; dst = wvb; base = 13312; }
  else                { src = wo; dst = wob; base = 13824; }
  const int i = (L - base) * 256 + threadIdx.x;   // 32B-pair index
  const float4 v0 = ((const float4*)src)[2 * i];
  const float4 v1 = ((const float4*)src)[2 * i + 1];
  ushort8v o;
  o[0] = f2bf(v0.x); o[1] = f2bf(v0.y); o[2] = f2bf(v0.z); o[3] = f2bf(v0.w);
  o[4] = f2bf(v1.x); o[5] = f2bf(v1.y); o[6] = f2bf(v1.z); o[7] = f2bf(v1.w);
  ((ushort8v*)dst)[i] = o;
}

// ---------------- mask dtype detection (bool push format is ambiguous) ----
__global__ void detect_mask_kernel(const unsigned int* __restrict__ m,
                                   unsigned int* __restrict__ flag) {
  __shared__ unsigned int not_int, not_flt;
  if (threadIdx.x == 0) { not_int = 0u; not_flt = 0u; }
  __syncthreads();
  unsigned int ni = 0u, nf = 0u;
  for (int j = 0; j < 4; ++j) {
    unsigned int w = m[threadIdx.x * 4 + j];
    if (w > 1u) ni = 1u;
    if (w != 0u && w != 0x3f800000u) nf = 1u;
  }
  if (ni) atomicOr(&not_int, 1u);
  if (nf) atomicOr(&not_flt, 1u);
  __syncthreads();
  if (threadIdx.x == 0) {
    unsigned int f = 1u;
    if (!not_int) f = 0u;
    else if (!not_flt) f = 2u;
    *flag = f;
  }
}

// ---------------- bit-pack mask: bit=1 <=> KEEP; 8 words per wave ---------
__global__ void pack_mask_kernel(const void* __restrict__ mraw,
                                 const unsigned int* __restrict__ flag,
                                 unsigned long long* __restrict__ bits) {
  const unsigned int f = *flag;
  const int lane = threadIdx.x & 63;
  const int w0 = ((blockIdx.x * blockDim.x + threadIdx.x) >> 6) * 8;
#pragma unroll
  for (int e = 0; e < 8; ++e) {
    const int t = (w0 + e) * 64 + lane;
    int v;
    if (f == 1u) v = (((const unsigned char*)mraw)[t] != 0);
    else         v = (((const unsigned int*)mraw)[t] != 0u);
    const unsigned long long b = __ballot(v == 0);   // keep-bit
    if (lane == 0) bits[w0 + e] = b;
  }
}

// ---------------- GEMM core, K=1024, BK=64, 2-phase prefetch --------------
template <int F32OUT>
__device__ __forceinline__ void gemm_core(const unsigned short* __restrict__ A,
                                          const unsigned short* __restrict__ B,
                                          const float* __restrict__ bias,
                                          void* __restrict__ Cout,
                                          int N, float scale, int biasM, int L) {
  __shared__ unsigned short As[2][128][64];   // 32KB, XOR-swizzled rows
  __shared__ unsigned short Bs[2][128][64];   // 32KB
  const int tid = threadIdx.x;
  const int wid = tid >> 6, lane = tid & 63;
  const int g = lane >> 4, c = lane & 15;
  const int wr = wid >> 1, wc = wid & 1;

  // XCD-pin swizzle (L%8 = xcd on MI355X): bijective L(0..511) -> (bx,by)
  const int xcd = L & 7;
  const int i5 = L >> 3;              // 0..63
  const int u = i5 & 7, v5 = i5 >> 3; // 0..7 each
  int bx, by;
  if ((N >> 7) == 8) { bx = u; by = xcd + 8 * v5; }   // 8x64 grid: pin A-row panel
  else               { bx = xcd + 8 * u; by = v5; }   // 64x8 grid: pin B-col panel
  const int m0 = by * 128, n0 = bx * 128;

  const floatx4 zero4 = {0.f, 0.f, 0.f, 0.f};
  floatx4 acc[4][4];
#pragma unroll
  for (int i = 0; i < 4; ++i)
#pragma unroll
    for (int j = 0; j < 4; ++j) acc[i][j] = zero4;

  const int r_ = tid >> 3;                                  // 0..31
  const int sb = ((tid & 7) * 16) ^ (((tid >> 3) & 7) << 4);
  const char* Asrc = (const char*)(A + (size_t)(m0 + r_) * 1024) + sb;
  const char* Bsrc = (const char*)(B + (size_t)(n0 + r_) * 1024) + sb;
  const size_t ROWP = (size_t)32 * 1024 * 2;

  auto stage = [&](int kt, int buf) {
    const size_t ko = (size_t)kt * 128;
#pragma unroll
    for (int p = 0; p < 4; ++p) {
      gload16(Asrc + ko + p * ROWP, (char*)&As[buf][0][0] + p * 4096 + tid * 16);
      gload16(Bsrc + ko + p * ROWP, (char*)&Bs[buf][0][0] + p * 4096 + tid * 16);
    }
  };

  stage(0, 0);
  __syncthreads();
  int cur = 0;
  for (int kt = 0; kt < 16; ++kt) {
    if (kt + 1 < 16) stage(kt + 1, cur ^ 1);   // loads fly across compute
    const char* abase = (const char*)&As[cur][0][0];
    const char* bbase = (const char*)&Bs[cur][0][0];
    bhalf8 a[2][4], b[2][4];
#pragma unroll
    for (int kk = 0; kk < 2; ++kk) {
#pragma unroll
      for (int i = 0; i < 4; ++i) {
        const int row = wr * 64 + i * 16 + c;
        a[kk][i] = *(const bhalf8*)(abase + row * 128 +
                                    ((kk * 64 + g * 16) ^ ((row & 7) << 4)));
      }
#pragma unroll
      for (int j = 0; j < 4; ++j) {
        const int row = wc * 64 + j * 16 + c;
        b[kk][j] = *(const bhalf8*)(bbase + row * 128 +
                                    ((kk * 64 + g * 16) ^ ((row & 7) << 4)));
      }
    }
#pragma unroll
    for (int kk = 0; kk < 2; ++kk)
#pragma unroll
      for (int i = 0; i < 4; ++i)
#pragma unroll
        for (int j = 0; j < 4; ++j)
          acc[i][j] = __builtin_amdgcn_mfma_f32_16x16x32_bf16(a[kk][i], b[kk][j], acc[i][j], 0, 0, 0);
    __syncthreads();
    cur ^= 1;
  }

  float bn[4] = {0.f, 0.f, 0.f, 0.f};
  if (!biasM) {
#pragma unroll
    for (int j = 0; j < 4; ++j) bn[j] = bias[n0 + wc * 64 + j * 16 + c];
  }
#pragma unroll
  for (int i = 0; i < 4; ++i) {
    float bm[4] = {0.f, 0.f, 0.f, 0.f};
    if (biasM) {
#pragma unroll
      for (int r = 0; r < 4; ++r) bm[r] = bias[m0 + wr * 64 + i * 16 + 4 * g + r];
    }
#pragma unroll
    for (int j = 0; j < 4; ++j) {
#pragma unroll
      for (int r = 0; r < 4; ++r) {
        const int m = m0 + wr * 64 + i * 16 + 4 * g + r;
        const int n = n0 + wc * 64 + j * 16 + c;
        const float v = (acc[i][j][r] + (biasM ? bm[r] : bn[j])) * scale;
        if (F32OUT) ((float*)Cout)[(size_t)m * N + n] = v;
        else ((unsigned short*)Cout)[(size_t)m * N + n] = f2bf(v);
      }
    }
  }
}

// merged QKV projections: jsel==3 -> grid 1536, j = L>>9; else j = jsel, grid 512
__global__ __launch_bounds__(256, 2)
void gemm_qkv_kernel(const unsigned short* __restrict__ Xq,
                     const unsigned short* __restrict__ Xk,
                     const unsigned short* __restrict__ Xv,
                     const unsigned short* __restrict__ Wqb,
                     const unsigned short* __restrict__ Wkb,
                     const unsigned short* __restrict__ Wvb,
                     const float* __restrict__ bq, const float* __restrict__ bk,
                     const float* __restrict__ bv,
                     unsigned short* __restrict__ Qb, unsigned short* __restrict__ Kb,
                     unsigned short* __restrict__ Vtb, float qscale, int jsel) {
  int j, L;
  if (jsel == 3) { j = blockIdx.x >> 9; L = blockIdx.x & 511; }
  else           { j = jsel; L = blockIdx.x; }
  const unsigned short* A = (j == 0) ? Xq : (j == 1) ? Xk : Wvb;
  const unsigned short* B = (j == 0) ? Wqb : (j == 1) ? Wkb : Xv;
  const float* bias = (j == 0) ? bq : (j == 1) ? bk : bv;
  unsigned short* C = (j == 0) ? Qb : (j == 1) ? Kb : Vtb;
  const int N = (j == 2) ? 8192 : 1024;
  const float scale = (j == 0) ? qscale : 1.0f;
  gemm_core<0>(A, B, bias, C, N, scale, (j == 2) ? 1 : 0, L);
}

__global__ __launch_bounds__(256, 2)
void gemm_out_kernel(const unsigned short* __restrict__ A,
                     const unsigned short* __restrict__ B,
                     const float* __restrict__ bias, float* __restrict__ C) {
  gemm_core<1>(A, B, bias, C, 1024, 1.0f, 0, blockIdx.x);
}

// ---------------- flash attention, 8 waves x 32 q-rows, 32x32x16 MFMA ------
// R15 = exact revert to the R13 attn (best measured: 104.8 us). KVBLK=64,
// 32KB LDS, one barrier per 64 kv. R14's KVBLK=128 regressed (occupancy
// 36->22%, FETCH 27->43MB): TLP + L2 locality beat barrier-halving here.
// Swapped QK^T; no max tracking; denominator via ones-column MFMA; KEEP-bit
// mask via sbfe+and; permlane32_swap A-frag exchange; XCD-pin swizzle.
__global__ __launch_bounds__(512, 2)
void attn_kernel(const unsigned short* __restrict__ Q,
                 const unsigned short* __restrict__ Kmat,
                 const unsigned short* __restrict__ Vt,
                 const unsigned long long* __restrict__ mbits,
                 unsigned short* __restrict__ O) {
  __shared__ unsigned short Ks[2][64][64];   // [buf][kv][dh], XOR-swizzled
  __shared__ unsigned short Vs[2][64][64];   // [buf][d][kv],  XOR-swizzled

  const int tid = threadIdx.x;
  const int wid = tid >> 6, lane = tid & 63;
  const int ql = lane & 31;
  const int hi = lane >> 5;

  // XCD-pin swizzle: xcd = L&7 (HW round-robin), bh fixed per xcd
  const int L = blockIdx.x;          // 0..511
  const int xcd = L & 7;
  const int s = L >> 3;              // 0..63
  const int bh = (s & 7) * 8 + xcd;  // 8 bh-streams per XCD
  const int qt = s >> 3;             // 0..7
  const int b = bh >> 4, h = bh & 15;
  const int q0 = qt * 256 + wid * 32;

  const unsigned short* Qb = Q + (size_t)(b * SEQ + q0) * D_MODEL + h * DHEAD;
  const unsigned short* Kb = Kmat + (size_t)(b * SEQ) * D_MODEL + h * DHEAD;
  const unsigned short* Vb = Vt + (size_t)(h * DHEAD) * (BATCH * SEQ) + (size_t)b * SEQ;

  // Q fragments: B-frag col=q=lane&31, k=dh=(lane>>5)*8+j
  bhalf8 qf[4];
#pragma unroll
  for (int ks = 0; ks < 4; ++ks)
    qf[ks] = *(const bhalf8*)(Qb + (size_t)ql * D_MODEL + ks * 16 + hi * 8);

  const floatx16 z16 = {0,0,0,0,0,0,0,0,0,0,0,0,0,0,0,0};
  floatx16 ot[2];
  ot[0] = z16; ot[1] = z16;
  floatx16 lt = z16;                       // softmax denominators (ones-MFMA)

  const short ONEB = (short)0x3F80;        // bf16 1.0
  const bhalf8 ones8 = {ONEB, ONEB, ONEB, ONEB, ONEB, ONEB, ONEB, ONEB};

  int koff[4];
#pragma unroll
  for (int ks = 0; ks < 4; ++ks)
    koff[ks] = ql * 128 + ((ks * 32 + hi * 16) ^ ((ql & 7) << 4));

  // staging: 512 threads x 1 gload16 each for K and V per tile (8KB each)
  const int sr = tid >> 3;                               // row 0..63
  const int sbz = ((tid & 7) * 16) ^ ((sr & 7) << 4);    // pre-swizzled src byte
  const char* Ksrc = (const char*)(Kb + (size_t)sr * D_MODEL) + sbz;
  const char* Vsrc = (const char*)(Vb + (size_t)sr * (BATCH * SEQ)) + sbz;
  const size_t KSTEP = (size_t)64 * D_MODEL * 2;
  const size_t VSTEP = 128;

  const int NT = SEQ / 64;
  gload16(Ksrc, (char*)&Ks[0][0][0] + tid * 16);
  gload16(Vsrc, (char*)&Vs[0][0][0] + tid * 16);
  __syncthreads();
  const char* kp = Ksrc + KSTEP;
  const char* vp = Vsrc + VSTEP;
  const unsigned long long* mp = mbits + (size_t)(q0 + ql) * (SEQ / 64);
  int cur = 0;

  for (int kt = 0; kt < NT; ++kt) {
    if (kt + 1 < NT) {
      gload16(kp, (char*)&Ks[cur ^ 1][0][0] + tid * 16);
      gload16(vp, (char*)&Vs[cur ^ 1][0][0] + tid * 16);
      kp += KSTEP;
      vp += VSTEP;
    }
    const unsigned long long mws = mp[kt] >> (4 * hi);   // keep-bits
    const unsigned int mlo = (unsigned int)mws;
    const unsigned int mhi32 = (unsigned int)(mws >> 32);

    const char* kbase = (const char*)&Ks[cur][0][0];
    const char* vbase = (const char*)&Vs[cur][0][0];

    // S^T = K * Q^T (first ks uses z16 as C-in -> no per-tile zero movs)
    floatx16 st[2];
    __builtin_amdgcn_s_setprio(1);
#pragma unroll
    for (int blk = 0; blk < 2; ++blk) {
      const bhalf8 kf0 = *(const bhalf8*)(kbase + koff[0] + blk * 4096);
      st[blk] = __builtin_amdgcn_mfma_f32_32x32x16_bf16(kf0, qf[0], z16, 0, 0, 0);
    }
#pragma unroll
    for (int ks = 1; ks < 4; ++ks) {
#pragma unroll
      for (int blk = 0; blk < 2; ++blk) {
        const bhalf8 kf = *(const bhalf8*)(kbase + koff[ks] + blk * 4096);
        st[blk] = __builtin_amdgcn_mfma_f32_32x32x16_bf16(kf, qf[ks], st[blk], 0, 0, 0);
      }
    }
    __builtin_amdgcn_s_setprio(0);

    // P = exp2(S), zero non-keep via sbfe(0/-1)+and, pack pairs (f2bf RNE)
    unsigned int w[2][8];
#pragma unroll
    for (int blk = 0; blk < 2; ++blk) {
      const unsigned int word = blk ? mhi32 : mlo;
#pragma unroll
      for (int i = 0; i < 8; ++i) {
        const int r0 = 2 * i, r1 = 2 * i + 1;
        const int c0 = (r0 & 3) + 8 * (r0 >> 2);
        const int c1 = c0 + 1;
        float p0 = __builtin_amdgcn_exp2f(st[blk][r0]);
        float p1 = __builtin_amdgcn_exp2f(st[blk][r1]);
        const unsigned int e0 = (unsigned int)__builtin_amdgcn_sbfe((int)word, c0, 1);
        const unsigned int e1 = (unsigned int)__builtin_amdgcn_sbfe((int)word, c1, 1);
        p0 = __builtin_bit_cast(float, __builtin_bit_cast(unsigned int, p0) & e0);
        p1 = __builtin_bit_cast(float, __builtin_bit_cast(unsigned int, p1) & e1);
        w[blk][i] = ((unsigned int)f2bf(p1) << 16) | (unsigned int)f2bf(p0);
      }
    }

    // O += P V; lt += P * ones. A-frags via permlane32_swap:
    // {awv0,awv2} = pl32(w[o],w[o+2]); {awv1,awv3} = pl32(w[o+1],w[o+3]).
    __builtin_amdgcn_s_setprio(1);
#pragma unroll
    for (int blk = 0; blk < 2; ++blk)
#pragma unroll
      for (int s2 = 0; s2 < 2; ++s2) {
        const int ks = blk * 2 + s2;
        const int o = s2 * 4;
        const uintx2 u2 = pl32(w[blk][o + 0], w[blk][o + 2]);
        const uintx2 v2 = pl32(w[blk][o + 1], w[blk][o + 3]);
        uintx4 awv;
        awv[0] = u2[0];  awv[1] = v2[0];  awv[2] = u2[1];  awv[3] = v2[1];
        const bhalf8 pa = __builtin_bit_cast(bhalf8, awv);
#pragma unroll
        for (int db = 0; db < 2; ++db) {
          const bhalf8 vf = *(const bhalf8*)(vbase + koff[ks] + db * 4096);
          ot[db] = __builtin_amdgcn_mfma_f32_32x32x16_bf16(pa, vf, ot[db], 0, 0, 0);
        }
        lt = __builtin_amdgcn_mfma_f32_32x32x16_bf16(pa, ones8, lt, 0, 0, 0);
      }
    __builtin_amdgcn_s_setprio(0);

    __syncthreads();   // drains prefetch vmcnt + protects both LDS buffers
    cur ^= 1;
  }

  // epilogue: O / l, write bf16 [b*T+q][h*64+d]
#pragma unroll
  for (int r = 0; r < 16; ++r) {
    const int qr = (r & 3) + 8 * (r >> 2) + 4 * hi;
    const float fi = 1.f / lt[r];
    unsigned short* orow = O + (size_t)(b * SEQ + q0 + qr) * D_MODEL + h * DHEAD + ql;
    orow[0]  = f2bf(ot[0][r] * fi);
    orow[32] = f2bf(ot[1][r] * fi);
  }
}

extern "C" void kernel_launch(void* const* d_in, const int* in_sizes, int n_in,
                              void* d_out, int out_size, void* d_ws, size_t ws_size,
                              hipStream_t stream) {
  (void)in_sizes; (void)n_in; (void)out_size;
  const float* query = (const float*)d_in[0];
  const float* key   = (const float*)d_in[1];
  const float* value = (const float*)d_in[2];
  const void*  mask  = d_in[3];
  const float* Wq = (const float*)d_in[4];
  const float* bq = (const float*)d_in[5];
  const float* Wk = (const float*)d_in[6];
  const float* bk = (const float*)d_in[7];
  const float* Wv = (const float*)d_in[8];
  const float* bv = (const float*)d_in[9];
  const float* Wo = (const float*)d_in[10];
  const float* bo = (const float*)d_in[11];

  const float QSCALE = 1.4426950408889634f / 32.0f;  // log2e / sqrt(D)
  const size_t XB = (size_t)8192 * 1024 * 2;          // 16 MB
  const size_t WB = (size_t)1024 * 1024 * 2;          // 2 MB
  const size_t MB = (size_t)2048 * 32 * 8;            // 512 KB

  char* ws = (char*)d_ws;
  size_t off = 0;
  auto alloc = [&](size_t bytes) {
    char* p = ws + off;
    off += (bytes + 255) & ~(size_t)255;
    return p;
  };

  // -------- path A: fused launches (needs ~105 MB) --------
  {
    size_t o2 = 0;
    auto need = [&](size_t b) { o2 += (b + 255) & ~(size_t)255; };
    need(XB); need(XB); need(XB);                 // Xq Xk Xv
    need(WB); need(WB); need(WB); need(WB);       // Wqb Wkb Wvb Wob
    need(XB); need(XB); need(XB);                 // Qb Kbf Vtb  (Ob aliases Xq)
    need(MB); need(256);
    if (o2 <= ws_size) {
      unsigned short* Xq  = (unsigned short*)alloc(XB);
      unsigned short* Xk  = (unsigned short*)alloc(XB);
      unsigned short* Xv  = (unsigned short*)alloc(XB);
      unsigned short* Wqb = (unsigned short*)alloc(WB);
      unsigned short* Wkb = (unsigned short*)alloc(WB);
      unsigned short* Wvb = (unsigned short*)alloc(WB);
      unsigned short* Wob = (unsigned short*)alloc(WB);
      unsigned short* Qb  = (unsigned short*)alloc(XB);
      unsigned short* Kbf = (unsigned short*)alloc(XB);
      unsigned short* Vtb = (unsigned short*)alloc(XB);
      unsigned long long* mbits = (unsigned long long*)alloc(MB);
      unsigned int* flag = (unsigned int*)alloc(256);
      unsigned short* Ob = Xq;   // lifetimes disjoint: Xq dead after gemm_qkv

      detect_mask_kernel<<<1, 256, 0, stream>>>((const unsigned int*)mask, flag);
      pack_mask_kernel<<<2048, 256, 0, stream>>>(mask, flag, mbits);
      cvt_all_kernel<<<14336, 256, 0, stream>>>(query, key, value, Wq, Wk, Wv, Wo,
                                                Xq, Xk, Xv, Wqb, Wkb, Wvb, Wob);
      gemm_qkv_kernel<<<1536, 256, 0, stream>>>(Xq, Xk, Xv, Wqb, Wkb, Wvb,
                                                bq, bk, bv, Qb, Kbf, Vtb, QSCALE, 3);
      attn_kernel<<<512, 512, 0, stream>>>(Qb, Kbf, Vtb, mbits, Ob);
      gemm_out_kernel<<<512, 256, 0, stream>>>(Ob, Wob, bo, (float*)d_out);
      return;
    }
  }

  // -------- path B: sequential, shared X buffer (~83 MB) --------
  unsigned short* Xb  = (unsigned short*)alloc(XB);
  unsigned short* Wb  = (unsigned short*)alloc(WB);
  unsigned short* Qb  = (unsigned short*)alloc(XB);
  unsigned short* Kbf = (unsigned short*)alloc(XB);
  unsigned short* Vtb = (unsigned short*)alloc(XB);
  unsigned short* Ob  = (unsigned short*)alloc(XB);
  unsigned long long* mbits = (unsigned long long*)alloc(MB);
  unsigned int* flag = (unsigned int*)alloc(256);
  if (off > ws_size) return;

  detect_mask_kernel<<<1, 256, 0, stream>>>((const unsigned int*)mask, flag);
  pack_mask_kernel<<<2048, 256, 0, stream>>>(mask, flag, mbits);

  cvt_bf16_kernel<<<8192, 256, 0, stream>>>(query, Xb, 2097152);
  cvt_bf16_kernel<<<1024, 256, 0, stream>>>(Wq, Wb, 262144);
  gemm_qkv_kernel<<<512, 256, 0, stream>>>(Xb, Xb, Xb, Wb, Wb, Wb, bq, bk, bv,
                                           Qb, Kbf, Vtb, QSCALE, 0);
  cvt_bf16_kernel<<<8192, 256, 0, stream>>>(key, Xb, 2097152);
  cvt_bf16_kernel<<<1024, 256, 0, stream>>>(Wk, Wb, 262144);
  gemm_qkv_kernel<<<512, 256, 0, stream>>>(Xb, Xb, Xb, Wb, Wb, Wb, bq, bk, bv,
                                           Qb, Kbf, Vtb, QSCALE, 1);
  cvt_bf16_kernel<<<8192, 256, 0, stream>>>(value, Xb, 2097152);
  cvt_bf16_kernel<<<1024, 256, 0, stream>>>(Wv, Wb, 262144);
  gemm_qkv_kernel<<<512, 256, 0, stream>>>(Xb, Xb, Xb, Wb, Wb, Wb, bq, bk, bv,
                                           Qb, Kbf, Vtb, QSCALE, 2);
  attn_kernel<<<512, 512, 0, stream>>>(Qb, Kbf, Vtb, mbits, Ob);
  cvt_bf16_kernel<<<1024, 256, 0, stream>>>(Wo, Wb, 262144);
  gemm_out_kernel<<<512, 256, 0, stream>>>(Ob, Wb, bo, (float*)d_out);
}